// Round 1
// baseline (3226.493 us; speedup 1.0000x reference)
//
#include <hip/hip_runtime.h>
#include <hip/hip_bf16.h>

// Problem constants (fixed by setup_inputs)
constexpr int Bn  = 8;
constexpr int Cc  = 512;
constexpr int ICc = 256;
constexpr int Hh  = 48;
constexpr int Ww  = 48;
constexpr int HWc = Hh * Ww;           // 2304
constexpr float BN_EPS = 1e-5f;

// ---------------------------------------------------------------------------
// Tiled fp32 GEMM for 1x1 conv:  Out[b] = W (MxK) * X[b] (K x HW) + bias
// TOUT=false: Out layout (B, M, HW); TOUT=true: Out layout (B, HW, M)
// Tiles: 64x64 output, K-step 16, 256 threads, 4x4 micro-tile per thread.
// ---------------------------------------------------------------------------
template <bool TOUT>
__global__ __launch_bounds__(256)
void conv_gemm(const float* __restrict__ W, const float* __restrict__ bias,
               const float* __restrict__ X, float* __restrict__ Out,
               int M, int K) {
    __shared__ float As[16][65];   // [k][m], padded to break write conflicts
    __shared__ float Bs[16][65];   // [k][n]

    const int b  = blockIdx.z;
    const float* Xb = X + (size_t)b * K * HWc;
    const int m0 = blockIdx.y * 64;
    const int n0 = blockIdx.x * 64;
    const int tid = threadIdx.x;
    const int tx = tid & 15;       // n-dir (4 cols each)
    const int ty = tid >> 4;       // m-dir (4 rows each)

    float acc[4][4];
#pragma unroll
    for (int i = 0; i < 4; ++i)
#pragma unroll
        for (int j = 0; j < 4; ++j) acc[i][j] = 0.f;

    for (int k0 = 0; k0 < K; k0 += 16) {
        // Load W tile (64 m x 16 k): consecutive threads read consecutive k
#pragma unroll
        for (int r = 0; r < 4; ++r) {
            int i = tid + r * 256;         // 0..1023
            int m = i >> 4, k = i & 15;
            As[k][m] = W[(size_t)(m0 + m) * K + (k0 + k)];
        }
        // Load X tile (16 k x 64 n): consecutive threads read consecutive n
#pragma unroll
        for (int r = 0; r < 4; ++r) {
            int i = tid + r * 256;
            int k = i >> 6, n = i & 63;
            Bs[k][n] = Xb[(size_t)(k0 + k) * HWc + (n0 + n)];
        }
        __syncthreads();
#pragma unroll
        for (int k = 0; k < 16; ++k) {
            float av[4], bv[4];
#pragma unroll
            for (int i = 0; i < 4; ++i) av[i] = As[k][ty * 4 + i];
#pragma unroll
            for (int j = 0; j < 4; ++j) bv[j] = Bs[k][tx * 4 + j];
#pragma unroll
            for (int i = 0; i < 4; ++i)
#pragma unroll
                for (int j = 0; j < 4; ++j)
                    acc[i][j] = fmaf(av[i], bv[j], acc[i][j]);
        }
        __syncthreads();
    }

    if (!TOUT) {
        float* Ob = Out + (size_t)b * M * HWc;   // (M, HW)
#pragma unroll
        for (int i = 0; i < 4; ++i) {
            int m = m0 + ty * 4 + i;
            float bvv = bias[m];
            float4 v = make_float4(acc[i][0] + bvv, acc[i][1] + bvv,
                                   acc[i][2] + bvv, acc[i][3] + bvv);
            *(float4*)&Ob[(size_t)m * HWc + n0 + tx * 4] = v;
        }
    } else {
        float* Ob = Out + (size_t)b * (size_t)M * HWc;  // (HW, M)
        float b0 = bias[m0 + ty * 4 + 0];
        float b1 = bias[m0 + ty * 4 + 1];
        float b2 = bias[m0 + ty * 4 + 2];
        float b3 = bias[m0 + ty * 4 + 3];
#pragma unroll
        for (int j = 0; j < 4; ++j) {
            int n = n0 + tx * 4 + j;
            float4 v = make_float4(acc[0][j] + b0, acc[1][j] + b1,
                                   acc[2][j] + b2, acc[3][j] + b3);
            *(float4*)&Ob[(size_t)n * M + m0 + ty * 4] = v;
        }
    }
}

// ---------------------------------------------------------------------------
// Attention: one block per (batch, query row).
//   theta_t: (B, HW, IC)   phi: (B, IC, HW)   g_t: (B, HW, IC)
//   y out  : (B, IC, HW)
// scores s[2304] live in LDS; softmax via block reduction; PV with lane=channel.
// ---------------------------------------------------------------------------
__global__ __launch_bounds__(256)
void attn_kernel(const float* __restrict__ theta_t, const float* __restrict__ phi,
                 const float* __restrict__ g_t, float* __restrict__ y) {
    const int b = blockIdx.x & 7;       // XCD swizzle: XCD i mostly sees batch i
    const int q = blockIdx.x >> 3;      // 0..2303
    const size_t bo = (size_t)b * ICc * HWc;

    __shared__ float trow[ICc];
    __shared__ float s[HWc];
    __shared__ float redm[4], reds[4];

    const int tid = threadIdx.x;        // 256 threads

    trow[tid] = theta_t[bo + (size_t)q * ICc + tid];
    __syncthreads();

    // QK^T: each thread owns 9 keys (tid + 256*i)
    float acc[9];
#pragma unroll
    for (int i = 0; i < 9; ++i) acc[i] = 0.f;
    const float* Pb = phi + bo;
    for (int c = 0; c < ICc; ++c) {
        float tv = trow[c];
        const float* pr = Pb + (size_t)c * HWc + tid;
#pragma unroll
        for (int i = 0; i < 9; ++i) acc[i] = fmaf(tv, pr[i * 256], acc[i]);
    }

    // Row max (wave64 shuffle + cross-wave LDS)
    float m = acc[0];
#pragma unroll
    for (int i = 1; i < 9; ++i) m = fmaxf(m, acc[i]);
#pragma unroll
    for (int off = 32; off; off >>= 1) m = fmaxf(m, __shfl_down(m, off, 64));
    if ((tid & 63) == 0) redm[tid >> 6] = m;
    __syncthreads();
    m = fmaxf(fmaxf(redm[0], redm[1]), fmaxf(redm[2], redm[3]));

    // exp + sum
    float sum = 0.f;
#pragma unroll
    for (int i = 0; i < 9; ++i) {
        float p = __expf(acc[i] - m);
        s[tid + i * 256] = p;
        sum += p;
    }
#pragma unroll
    for (int off = 32; off; off >>= 1) sum += __shfl_down(sum, off, 64);
    if ((tid & 63) == 0) reds[tid >> 6] = sum;
    __syncthreads();
    const float rinv = 1.0f / (reds[0] + reds[1] + reds[2] + reds[3]);

    // PV: lane = channel; g_t[k][c] coalesced across lanes, s[k] LDS broadcast
    const float* Gb = g_t + bo;
    float a = 0.f;
#pragma unroll 8
    for (int k = 0; k < HWc; ++k)
        a = fmaf(s[k], Gb[(size_t)k * ICc + tid], a);

    y[bo + (size_t)tid * HWc + q] = a * rinv;
}

// ---------------------------------------------------------------------------
// BN stats: one block per channel o. stats[o]=mean, stats[C+o]=rstd
// ---------------------------------------------------------------------------
__global__ __launch_bounds__(256)
void bn_stats(const float* __restrict__ wy, float* __restrict__ stats) {
    const int o = blockIdx.x;
    const int tid = threadIdx.x;
    float s0 = 0.f, s1 = 0.f;
    for (int b = 0; b < Bn; ++b) {
        const float* r = wy + (size_t)b * Cc * HWc + (size_t)o * HWc;
        for (int p = tid; p < HWc; p += 256) {
            float v = r[p];
            s0 += v;
            s1 = fmaf(v, v, s1);
        }
    }
#pragma unroll
    for (int off = 32; off; off >>= 1) {
        s0 += __shfl_down(s0, off, 64);
        s1 += __shfl_down(s1, off, 64);
    }
    __shared__ float r0[4], r1[4];
    if ((tid & 63) == 0) { r0[tid >> 6] = s0; r1[tid >> 6] = s1; }
    __syncthreads();
    if (tid == 0) {
        float sum = r0[0] + r0[1] + r0[2] + r0[3];
        float sq  = r1[0] + r1[1] + r1[2] + r1[3];
        const float N = (float)(Bn * HWc);
        float mean = sum / N;
        float var  = sq / N - mean * mean;
        stats[o]       = mean;
        stats[Cc + o]  = rsqrtf(var + BN_EPS);
    }
}

// ---------------------------------------------------------------------------
// Normalize + affine + residual, float4 vectorized
// ---------------------------------------------------------------------------
__global__ __launch_bounds__(256)
void bn_apply(const float* __restrict__ wy, const float* __restrict__ x,
              const float* __restrict__ stats, const float* __restrict__ gamma,
              const float* __restrict__ beta, float* __restrict__ out) {
    const size_t i4 = (size_t)blockIdx.x * 256 + threadIdx.x;  // float4 index
    const size_t base = i4 * 4;
    const int o = (int)((base / HWc) % Cc);   // HW divisible by 4 -> o uniform
    const float mean = stats[o];
    const float rstd = stats[Cc + o];
    const float ga = gamma[o];
    const float be = beta[o];
    const float4 w4 = ((const float4*)wy)[i4];
    const float4 x4 = ((const float4*)x)[i4];
    float4 r;
    r.x = (w4.x - mean) * rstd * ga + be + x4.x;
    r.y = (w4.y - mean) * rstd * ga + be + x4.y;
    r.z = (w4.z - mean) * rstd * ga + be + x4.z;
    r.w = (w4.w - mean) * rstd * ga + be + x4.w;
    ((float4*)out)[i4] = r;
}

// ---------------------------------------------------------------------------
extern "C" void kernel_launch(void* const* d_in, const int* in_sizes, int n_in,
                              void* d_out, int out_size, void* d_ws, size_t ws_size,
                              hipStream_t stream) {
    const float* x     = (const float*)d_in[0];
    const float* g_w   = (const float*)d_in[1];
    const float* g_b   = (const float*)d_in[2];
    const float* th_w  = (const float*)d_in[3];
    const float* th_b  = (const float*)d_in[4];
    const float* ph_w  = (const float*)d_in[5];
    const float* ph_b  = (const float*)d_in[6];
    const float* w_w   = (const float*)d_in[7];
    const float* w_b   = (const float*)d_in[8];
    const float* gamma = (const float*)d_in[9];
    const float* beta  = (const float*)d_in[10];

    float* ws = (float*)d_ws;
    const size_t SZ1 = (size_t)Bn * ICc * HWc;   // 4,718,592 floats
    float* theta_t = ws;                 // (B, HW, IC)
    float* phi     = ws + SZ1;           // (B, IC, HW)
    float* g_t     = ws + 2 * SZ1;       // (B, HW, IC)
    float* y       = ws + 3 * SZ1;       // (B, IC, HW)
    float* wy      = ws + 4 * SZ1;       // (B, C, HW)  = 2*SZ1 floats
    float* stats   = ws + 6 * SZ1;       // 2*C floats

    dim3 blk(256);

    // 1x1 convs: theta (transposed out), phi (normal), g (transposed out)
    dim3 g1(HWc / 64, ICc / 64, Bn);     // (36, 4, 8)
    conv_gemm<true ><<<g1, blk, 0, stream>>>(th_w, th_b, x, theta_t, ICc, Cc);
    conv_gemm<false><<<g1, blk, 0, stream>>>(ph_w, ph_b, x, phi,     ICc, Cc);
    conv_gemm<true ><<<g1, blk, 0, stream>>>(g_w,  g_b,  x, g_t,     ICc, Cc);

    // attention: softmax(theta^T phi) * g
    attn_kernel<<<dim3(HWc * Bn), blk, 0, stream>>>(theta_t, phi, g_t, y);

    // W conv: (C x IC) * y
    dim3 g2(HWc / 64, Cc / 64, Bn);      // (36, 8, 8)
    conv_gemm<false><<<g2, blk, 0, stream>>>(w_w, w_b, y, wy, Cc, ICc);

    // BatchNorm (training stats) + affine + residual
    bn_stats<<<dim3(Cc), blk, 0, stream>>>(wy, stats);
    bn_apply<<<dim3((Bn * Cc * HWc) / 4 / 256), blk, 0, stream>>>(
        wy, x, stats, gamma, beta, (float*)d_out);
}

// Round 2
// 674.016 us; speedup vs baseline: 4.7870x; 4.7870x over previous
//
#include <hip/hip_runtime.h>
#include <hip/hip_bf16.h>
#include <stdint.h>

// Problem constants (fixed by setup_inputs)
constexpr int Bn  = 8;
constexpr int Cc  = 512;
constexpr int ICc = 256;
constexpr int HWc = 48 * 48;           // 2304
constexpr float BN_EPS = 1e-5f;

typedef unsigned short u16;
typedef __attribute__((ext_vector_type(8))) short short8;   // 8 bf16 (4 VGPRs)
typedef __attribute__((ext_vector_type(4))) float f32x4;    // MFMA C/D frag

__device__ __forceinline__ u16 f2bf(float f) {
    uint32_t u = __builtin_bit_cast(uint32_t, f);
    u += 0x7fffu + ((u >> 16) & 1u);     // RNE
    return (u16)(u >> 16);
}
__device__ __forceinline__ float bf2f(u16 h) {
    uint32_t u = ((uint32_t)h) << 16;
    return __builtin_bit_cast(float, u);
}
// async global->LDS, 16B per lane; lds dst must be wave-uniform base (HW adds lane*16)
__device__ __forceinline__ void load_lds16(const void* g, void* l) {
    __builtin_amdgcn_global_load_lds(
        (const __attribute__((address_space(1))) void*)(uintptr_t)g,
        (__attribute__((address_space(3))) void*)(uintptr_t)l, 16, 0, 0);
}

// ---------------------------------------------------------------------------
// Tiled fp32 GEMM for 1x1 conv: Out[b] = W (MxK) * X[b] (K x HW) + bias
// TOUT=false: Out (B, M, HW); TOUT=true: Out (B, HW, M). BF16OUT: store bf16.
// ---------------------------------------------------------------------------
template <bool TOUT, bool BF16OUT>
__global__ __launch_bounds__(256)
void conv_gemm(const float* __restrict__ W, const float* __restrict__ bias,
               const float* __restrict__ X, void* __restrict__ Out,
               int M, int K) {
    __shared__ float As[16][65];
    __shared__ float Bs[16][65];

    const int b  = blockIdx.z;
    const float* Xb = X + (size_t)b * K * HWc;
    const int m0 = blockIdx.y * 64;
    const int n0 = blockIdx.x * 64;
    const int tid = threadIdx.x;
    const int tx = tid & 15;
    const int ty = tid >> 4;

    float acc[4][4];
#pragma unroll
    for (int i = 0; i < 4; ++i)
#pragma unroll
        for (int j = 0; j < 4; ++j) acc[i][j] = 0.f;

    for (int k0 = 0; k0 < K; k0 += 16) {
#pragma unroll
        for (int r = 0; r < 4; ++r) {
            int i = tid + r * 256;
            int m = i >> 4, k = i & 15;
            As[k][m] = W[(size_t)(m0 + m) * K + (k0 + k)];
        }
#pragma unroll
        for (int r = 0; r < 4; ++r) {
            int i = tid + r * 256;
            int k = i >> 6, n = i & 63;
            Bs[k][n] = Xb[(size_t)(k0 + k) * HWc + (n0 + n)];
        }
        __syncthreads();
#pragma unroll
        for (int k = 0; k < 16; ++k) {
            float av[4], bv[4];
#pragma unroll
            for (int i = 0; i < 4; ++i) av[i] = As[k][ty * 4 + i];
#pragma unroll
            for (int j = 0; j < 4; ++j) bv[j] = Bs[k][tx * 4 + j];
#pragma unroll
            for (int i = 0; i < 4; ++i)
#pragma unroll
                for (int j = 0; j < 4; ++j)
                    acc[i][j] = fmaf(av[i], bv[j], acc[i][j]);
        }
        __syncthreads();
    }

    if (!TOUT) {
        if (!BF16OUT) {
            float* Ob = (float*)Out + (size_t)b * M * HWc;
#pragma unroll
            for (int i = 0; i < 4; ++i) {
                int m = m0 + ty * 4 + i;
                float bvv = bias[m];
                float4 v = make_float4(acc[i][0] + bvv, acc[i][1] + bvv,
                                       acc[i][2] + bvv, acc[i][3] + bvv);
                *(float4*)&Ob[(size_t)m * HWc + n0 + tx * 4] = v;
            }
        } else {
            u16* Ob = (u16*)Out + (size_t)b * M * HWc;
#pragma unroll
            for (int i = 0; i < 4; ++i) {
                int m = m0 + ty * 4 + i;
                float bvv = bias[m];
                ushort4 v;
                v.x = f2bf(acc[i][0] + bvv); v.y = f2bf(acc[i][1] + bvv);
                v.z = f2bf(acc[i][2] + bvv); v.w = f2bf(acc[i][3] + bvv);
                *(ushort4*)&Ob[(size_t)m * HWc + n0 + tx * 4] = v;
            }
        }
    } else {
        float b0 = bias[m0 + ty * 4 + 0];
        float b1 = bias[m0 + ty * 4 + 1];
        float b2 = bias[m0 + ty * 4 + 2];
        float b3 = bias[m0 + ty * 4 + 3];
        if (!BF16OUT) {
            float* Ob = (float*)Out + (size_t)b * (size_t)M * HWc;
#pragma unroll
            for (int j = 0; j < 4; ++j) {
                int n = n0 + tx * 4 + j;
                float4 v = make_float4(acc[0][j] + b0, acc[1][j] + b1,
                                       acc[2][j] + b2, acc[3][j] + b3);
                *(float4*)&Ob[(size_t)n * M + m0 + ty * 4] = v;
            }
        } else {
            u16* Ob = (u16*)Out + (size_t)b * (size_t)M * HWc;
#pragma unroll
            for (int j = 0; j < 4; ++j) {
                int n = n0 + tx * 4 + j;
                ushort4 v;
                v.x = f2bf(acc[0][j] + b0); v.y = f2bf(acc[1][j] + b1);
                v.z = f2bf(acc[2][j] + b2); v.w = f2bf(acc[3][j] + b3);
                *(ushort4*)&Ob[(size_t)n * M + m0 + ty * 4] = v;
            }
        }
    }
}

// ---------------------------------------------------------------------------
// bf16 MFMA GEMM: C[m][n] = sum_k A[m][k] * B[n][k]
//   A: (M,K) bf16 row-major, B: (N,K) bf16 row-major, both K-contiguous.
//   128x128 tile, 256 threads (4 waves, each 64x64 = 4x4 mfma 16x16x32 tiles).
//   Staging via global_load_lds width=16.
// STORE==0: bf16 C[m][n] (ldC);  STORE==2: fp32 transposed C[n][m] (ldC = M-ld)
// ---------------------------------------------------------------------------
template <int STORE>
__global__ __launch_bounds__(256, 2)
void mfma_gemm(const u16* __restrict__ A, const u16* __restrict__ B,
               void* __restrict__ Cout, int K, int ldA, int ldB, int ldC,
               size_t sA, size_t sB, size_t sC) {
    __shared__ __align__(16) u16 As[128 * 32];
    __shared__ __align__(16) u16 Bs[128 * 32];
    const int bz = blockIdx.z;
    const int m0 = blockIdx.y * 128, n0 = blockIdx.x * 128;
    const u16* Ab = A + (size_t)bz * sA + (size_t)m0 * ldA;
    const u16* Bb = B + (size_t)bz * sB + (size_t)n0 * ldB;
    const int tid = threadIdx.x, lane = tid & 63, w = tid >> 6;
    const int wm = (w & 1) * 64, wn = (w >> 1) * 64;
    const int quad = lane >> 4, m16 = lane & 15;

    f32x4 acc[4][4];
#pragma unroll
    for (int i = 0; i < 4; ++i)
#pragma unroll
        for (int j = 0; j < 4; ++j) acc[i][j] = (f32x4){0.f, 0.f, 0.f, 0.f};

    // staging lane mapping: linear slot L -> row = L>>2, k-chunk = (L&3)*8
    const int L0 = 2 * w * 64 + lane;
    const int L1 = L0 + 64;
    const int r0 = L0 >> 2, c0 = (L0 & 3) * 8;
    const int r1 = L1 >> 2, c1 = (L1 & 3) * 8;

    for (int k0 = 0; k0 < K; k0 += 32) {
        load_lds16(Ab + (size_t)r0 * ldA + k0 + c0, &As[2 * w * 512]);
        load_lds16(Ab + (size_t)r1 * ldA + k0 + c1, &As[(2 * w + 1) * 512]);
        load_lds16(Bb + (size_t)r0 * ldB + k0 + c0, &Bs[2 * w * 512]);
        load_lds16(Bb + (size_t)r1 * ldB + k0 + c1, &Bs[(2 * w + 1) * 512]);
        __syncthreads();

        short8 af[4], bfv[4];
#pragma unroll
        for (int i = 0; i < 4; ++i)
            af[i] = *(const short8*)&As[(wm + i * 16 + m16) * 32 + quad * 8];
#pragma unroll
        for (int j = 0; j < 4; ++j)
            bfv[j] = *(const short8*)&Bs[(wn + j * 16 + m16) * 32 + quad * 8];
#pragma unroll
        for (int i = 0; i < 4; ++i)
#pragma unroll
            for (int j = 0; j < 4; ++j)
                acc[i][j] = __builtin_amdgcn_mfma_f32_16x16x32_bf16(
                    af[i], bfv[j], acc[i][j], 0, 0, 0);
        __syncthreads();
    }

    // C/D layout (m89-verified): col(n)=lane&15, row(m)=(lane>>4)*4+reg
    if (STORE == 0) {
        u16* C = (u16*)Cout + (size_t)bz * sC;
#pragma unroll
        for (int i = 0; i < 4; ++i) {
            int m = m0 + wm + i * 16 + quad * 4;
#pragma unroll
            for (int j = 0; j < 4; ++j) {
                int n = n0 + wn + j * 16 + m16;
#pragma unroll
                for (int r = 0; r < 4; ++r)
                    C[(size_t)(m + r) * ldC + n] = f2bf(acc[i][j][r]);
            }
        }
    } else {
        float* C = (float*)Cout + (size_t)bz * sC;
#pragma unroll
        for (int j = 0; j < 4; ++j) {
            int n = n0 + wn + j * 16 + m16;
#pragma unroll
            for (int i = 0; i < 4; ++i) {
                int m = m0 + wm + i * 16 + quad * 4;
                *(f32x4*)&C[(size_t)n * ldC + m] = acc[i][j];  // 4 consecutive m
            }
        }
    }
}

// ---------------------------------------------------------------------------
// In-place row softmax on bf16 S (rows of 2304). 192 threads, 12 elems each.
// ---------------------------------------------------------------------------
__global__ __launch_bounds__(192)
void softmax_rows(u16* __restrict__ S) {
    const int b = blockIdx.x & 7;
    const int q = blockIdx.x >> 3;
    u16* row = S + ((size_t)b * HWc + q) * (size_t)HWc;
    const int tid = threadIdx.x;

    float v[12];
#pragma unroll
    for (int c = 0; c < 3; ++c) {
        uint2 raw = *(const uint2*)&row[(c * 192 + tid) * 4];
        v[c * 4 + 0] = bf2f((u16)(raw.x & 0xffff));
        v[c * 4 + 1] = bf2f((u16)(raw.x >> 16));
        v[c * 4 + 2] = bf2f((u16)(raw.y & 0xffff));
        v[c * 4 + 3] = bf2f((u16)(raw.y >> 16));
    }
    float m = v[0];
#pragma unroll
    for (int i = 1; i < 12; ++i) m = fmaxf(m, v[i]);
#pragma unroll
    for (int off = 32; off; off >>= 1) m = fmaxf(m, __shfl_down(m, off, 64));
    __shared__ float redm[3], reds[3];
    if ((tid & 63) == 0) redm[tid >> 6] = m;
    __syncthreads();
    m = fmaxf(fmaxf(redm[0], redm[1]), redm[2]);

    float s = 0.f;
#pragma unroll
    for (int i = 0; i < 12; ++i) { v[i] = __expf(v[i] - m); s += v[i]; }
#pragma unroll
    for (int off = 32; off; off >>= 1) s += __shfl_down(s, off, 64);
    if ((tid & 63) == 0) reds[tid >> 6] = s;
    __syncthreads();
    const float rinv = 1.0f / (reds[0] + reds[1] + reds[2]);

#pragma unroll
    for (int c = 0; c < 3; ++c) {
        uint2 o;
        o.x = (uint32_t)f2bf(v[c * 4 + 0] * rinv) |
              ((uint32_t)f2bf(v[c * 4 + 1] * rinv) << 16);
        o.y = (uint32_t)f2bf(v[c * 4 + 2] * rinv) |
              ((uint32_t)f2bf(v[c * 4 + 3] * rinv) << 16);
        *(uint2*)&row[(c * 192 + tid) * 4] = o;
    }
}

// ---------------------------------------------------------------------------
// BN stats: one block per channel o. stats[o]=mean, stats[C+o]=rstd
// ---------------------------------------------------------------------------
__global__ __launch_bounds__(256)
void bn_stats(const float* __restrict__ wy, float* __restrict__ stats) {
    const int o = blockIdx.x;
    const int tid = threadIdx.x;
    float s0 = 0.f, s1 = 0.f;
    for (int b = 0; b < Bn; ++b) {
        const float* r = wy + (size_t)b * Cc * HWc + (size_t)o * HWc;
        for (int p = tid; p < HWc; p += 256) {
            float v = r[p];
            s0 += v;
            s1 = fmaf(v, v, s1);
        }
    }
#pragma unroll
    for (int off = 32; off; off >>= 1) {
        s0 += __shfl_down(s0, off, 64);
        s1 += __shfl_down(s1, off, 64);
    }
    __shared__ float r0[4], r1[4];
    if ((tid & 63) == 0) { r0[tid >> 6] = s0; r1[tid >> 6] = s1; }
    __syncthreads();
    if (tid == 0) {
        float sum = r0[0] + r0[1] + r0[2] + r0[3];
        float sq  = r1[0] + r1[1] + r1[2] + r1[3];
        const float N = (float)(Bn * HWc);
        float mean = sum / N;
        float var  = sq / N - mean * mean;
        stats[o]      = mean;
        stats[Cc + o] = rsqrtf(var + BN_EPS);
    }
}

__global__ __launch_bounds__(256)
void bn_apply(const float* __restrict__ wy, const float* __restrict__ x,
              const float* __restrict__ stats, const float* __restrict__ gamma,
              const float* __restrict__ beta, float* __restrict__ out) {
    const size_t i4 = (size_t)blockIdx.x * 256 + threadIdx.x;
    const size_t base = i4 * 4;
    const int o = (int)((base / HWc) % Cc);
    const float mean = stats[o];
    const float rstd = stats[Cc + o];
    const float ga = gamma[o];
    const float be = beta[o];
    const float4 w4 = ((const float4*)wy)[i4];
    const float4 x4 = ((const float4*)x)[i4];
    float4 r;
    r.x = (w4.x - mean) * rstd * ga + be + x4.x;
    r.y = (w4.y - mean) * rstd * ga + be + x4.y;
    r.z = (w4.z - mean) * rstd * ga + be + x4.z;
    r.w = (w4.w - mean) * rstd * ga + be + x4.w;
    ((float4*)out)[i4] = r;
}

// ---------------------------------------------------------------------------
extern "C" void kernel_launch(void* const* d_in, const int* in_sizes, int n_in,
                              void* d_out, int out_size, void* d_ws, size_t ws_size,
                              hipStream_t stream) {
    const float* x     = (const float*)d_in[0];
    const float* g_w   = (const float*)d_in[1];
    const float* g_b   = (const float*)d_in[2];
    const float* th_w  = (const float*)d_in[3];
    const float* th_b  = (const float*)d_in[4];
    const float* ph_w  = (const float*)d_in[5];
    const float* ph_b  = (const float*)d_in[6];
    const float* w_w   = (const float*)d_in[7];
    const float* w_b   = (const float*)d_in[8];
    const float* gamma = (const float*)d_in[9];
    const float* beta  = (const float*)d_in[10];

    // workspace layout (bytes); total 113,250,304 B (same footprint as round 1)
    //   [0, 9.44M)   theta_t bf16 (B,HW,IC)  -> reused by y fp32 (B,IC,HW)
    //   [9.44M, 18.9M) phi_t bf16 (B,HW,IC)  -> (y second half)
    //   [18.9M, 28.3M) g bf16 (B,IC,HW)
    //   [28.3M, 113.2M) S/P bf16 (B,HW,HW)   -> reused by wy fp32 (B,C,HW)
    //   [113.2M, +4K) stats
    char* base = (char*)d_ws;
    const size_t SZT = (size_t)Bn * HWc * ICc * 2;       // 9,437,184
    u16* tht = (u16*)base;
    u16* pht = (u16*)(base + SZT);
    u16* gbf = (u16*)(base + 2 * SZT);
    u16* S   = (u16*)(base + 3 * SZT);                   // 84,934,656 B
    float* y  = (float*)base;                            // (B,IC,HW) fp32 = 2*SZT
    float* wy = (float*)(base + 3 * SZT);                // (B,C,HW) fp32
    float* stats = (float*)(base + 3 * SZT + (size_t)Bn * HWc * HWc * 2);

    dim3 blk(256);

    // 1x1 convs -> bf16: theta_t, phi_t (HW,IC); g (IC,HW)
    dim3 g1(HWc / 64, ICc / 64, Bn);
    conv_gemm<true , true ><<<g1, blk, 0, stream>>>(th_w, th_b, x, tht, ICc, Cc);
    conv_gemm<true , true ><<<g1, blk, 0, stream>>>(ph_w, ph_b, x, pht, ICc, Cc);
    conv_gemm<false, true ><<<g1, blk, 0, stream>>>(g_w,  g_b,  x, gbf, ICc, Cc);

    // S = theta_t . phi_t^T  (M=N=2304, K=256), bf16 out
    mfma_gemm<0><<<dim3(18, 18, Bn), blk, 0, stream>>>(
        tht, pht, S, /*K*/ICc, /*ldA*/ICc, /*ldB*/ICc, /*ldC*/HWc,
        (size_t)HWc * ICc, (size_t)HWc * ICc, (size_t)HWc * HWc);

    // softmax rows, in place
    softmax_rows<<<dim3(Bn * HWc), dim3(192), 0, stream>>>(S);

    // y^T: y[ic][q] = sum_k P[q][k] g[ic][k]  (M=2304 q, N=256 ic, K=2304)
    mfma_gemm<2><<<dim3(ICc / 128, HWc / 128, Bn), blk, 0, stream>>>(
        S, gbf, y, /*K*/HWc, /*ldA*/HWc, /*ldB*/HWc, /*ldC*/HWc,
        (size_t)HWc * HWc, (size_t)ICc * HWc, (size_t)ICc * HWc);

    // W conv (fp32): wy = w_w . y   (reads y as (K=IC, HW))
    conv_gemm<false, false><<<dim3(HWc / 64, Cc / 64, Bn), blk, 0, stream>>>(
        w_w, w_b, y, wy, Cc, ICc);

    // BatchNorm (training stats) + affine + residual
    bn_stats<<<dim3(Cc), blk, 0, stream>>>(wy, stats);
    bn_apply<<<dim3((Bn * Cc * HWc) / 4 / 256), blk, 0, stream>>>(
        wy, x, stats, gamma, beta, (float*)d_out);
}

// Round 3
// 376.644 us; speedup vs baseline: 8.5664x; 1.7895x over previous
//
#include <hip/hip_runtime.h>
#include <hip/hip_bf16.h>
#include <stdint.h>

// Problem constants (fixed by setup_inputs)
constexpr int Bn  = 8;
constexpr int Cc  = 512;
constexpr int ICc = 256;
constexpr int HWc = 48 * 48;           // 2304
constexpr float BN_EPS = 1e-5f;

typedef unsigned short u16;
typedef __attribute__((ext_vector_type(8))) short short8;   // 8 bf16 (4 VGPRs)
typedef __attribute__((ext_vector_type(4))) float f32x4;    // MFMA C/D frag

__device__ __forceinline__ u16 f2bf(float f) {
    uint32_t u = __builtin_bit_cast(uint32_t, f);
    u += 0x7fffu + ((u >> 16) & 1u);     // RNE
    return (u16)(u >> 16);
}
__device__ __forceinline__ float bf2f(u16 h) {
    uint32_t u = ((uint32_t)h) << 16;
    return __builtin_bit_cast(float, u);
}
// async global->LDS, 16B per lane; lds dst is wave-uniform base (HW adds lane*16)
__device__ __forceinline__ void load_lds16(const void* g, void* l) {
    __builtin_amdgcn_global_load_lds(
        (const __attribute__((address_space(1))) void*)(uintptr_t)g,
        (__attribute__((address_space(3))) void*)(uintptr_t)l, 16, 0, 0);
}

// ---------------------------------------------------------------------------
// Cast 3 weight matrices fp32 -> bf16 (each 256x512 = 131072 elems = 32768 f4)
// ---------------------------------------------------------------------------
__global__ __launch_bounds__(256)
void cast3_weights(const float* __restrict__ a, const float* __restrict__ b,
                   const float* __restrict__ c, u16* __restrict__ out) {
    int idx = blockIdx.x * 256 + threadIdx.x;          // 0..98303
    int which = idx >> 15, off = idx & 32767;
    const float4* src = (which == 0 ? (const float4*)a
                        : which == 1 ? (const float4*)b : (const float4*)c) + off;
    float4 v = *src;
    ushort4 o;
    o.x = f2bf(v.x); o.y = f2bf(v.y); o.z = f2bf(v.z); o.w = f2bf(v.w);
    ((ushort4*)out)[idx] = o;
}

__global__ __launch_bounds__(256)
void cast1_weight(const float* __restrict__ a, u16* __restrict__ out) {
    int idx = blockIdx.x * 256 + threadIdx.x;          // 0..32767
    float4 v = ((const float4*)a)[idx];
    ushort4 o;
    o.x = f2bf(v.x); o.y = f2bf(v.y); o.z = f2bf(v.z); o.w = f2bf(v.w);
    ((ushort4*)out)[idx] = o;
}

// ---------------------------------------------------------------------------
// x (B,C,HW) fp32 -> xt (B,HW,C) bf16, 32x32 LDS-tiled transpose
// ---------------------------------------------------------------------------
__global__ __launch_bounds__(256)
void transpose_cast_x(const float* __restrict__ x, u16* __restrict__ xt) {
    __shared__ float t[32][33];
    const int b = blockIdx.z;
    const int p0 = blockIdx.x * 32;     // HW dir
    const int c0 = blockIdx.y * 32;     // C dir
    const int tx = threadIdx.x & 31, ty = threadIdx.x >> 5;   // ty 0..7
    const float* xb = x + (size_t)b * Cc * HWc;
#pragma unroll
    for (int r = 0; r < 32; r += 8)
        t[ty + r][tx] = xb[(size_t)(c0 + ty + r) * HWc + p0 + tx];
    __syncthreads();
    u16* xtb = xt + (size_t)b * HWc * Cc;
#pragma unroll
    for (int r = 0; r < 32; r += 8)
        xtb[(size_t)(p0 + ty + r) * Cc + c0 + tx] = f2bf(t[tx][ty + r]);
}

// ---------------------------------------------------------------------------
// bf16 MFMA GEMM: C[m][n] = sum_k A[m][k] * B[n][k] (+ bias)
//   A: (M,K) bf16 row-major, B: (N,K) bf16 row-major, both K-contiguous.
//   128x128 tile, 256 threads (4 waves, each 64x64 = 4x4 mfma 16x16x32 tiles).
// STORE==0: bf16 C row-major; STORE==1: fp32 C row-major.
// bias_mode: 0 none, 1 per-n, 2 per-m.
// ---------------------------------------------------------------------------
template <int STORE>
__global__ __launch_bounds__(256, 2)
void mfma_gemm(const u16* __restrict__ A, const u16* __restrict__ B,
               void* __restrict__ Cout, const float* __restrict__ bias,
               int bias_mode, int K, int ldA, int ldB, int ldC,
               size_t sA, size_t sB, size_t sC) {
    __shared__ __align__(16) u16 As[128 * 32];
    __shared__ __align__(16) u16 Bs[128 * 32];
    const int bz = blockIdx.z;
    const int m0 = blockIdx.y * 128, n0 = blockIdx.x * 128;
    const u16* Ab = A + (size_t)bz * sA + (size_t)m0 * ldA;
    const u16* Bb = B + (size_t)bz * sB + (size_t)n0 * ldB;
    const int tid = threadIdx.x, lane = tid & 63, w = tid >> 6;
    const int wm = (w & 1) * 64, wn = (w >> 1) * 64;
    const int quad = lane >> 4, m16 = lane & 15;

    f32x4 acc[4][4];
#pragma unroll
    for (int i = 0; i < 4; ++i)
#pragma unroll
        for (int j = 0; j < 4; ++j) acc[i][j] = (f32x4){0.f, 0.f, 0.f, 0.f};

    // staging lane mapping: linear slot L -> row = L>>2, k-chunk = (L&3)*8
    const int L0 = 2 * w * 64 + lane;
    const int L1 = L0 + 64;
    const int r0 = L0 >> 2, c0 = (L0 & 3) * 8;
    const int r1 = L1 >> 2, c1 = (L1 & 3) * 8;

    for (int k0 = 0; k0 < K; k0 += 32) {
        load_lds16(Ab + (size_t)r0 * ldA + k0 + c0, &As[2 * w * 512]);
        load_lds16(Ab + (size_t)r1 * ldA + k0 + c1, &As[(2 * w + 1) * 512]);
        load_lds16(Bb + (size_t)r0 * ldB + k0 + c0, &Bs[2 * w * 512]);
        load_lds16(Bb + (size_t)r1 * ldB + k0 + c1, &Bs[(2 * w + 1) * 512]);
        __syncthreads();

        short8 af[4], bfv[4];
#pragma unroll
        for (int i = 0; i < 4; ++i)
            af[i] = *(const short8*)&As[(wm + i * 16 + m16) * 32 + quad * 8];
#pragma unroll
        for (int j = 0; j < 4; ++j)
            bfv[j] = *(const short8*)&Bs[(wn + j * 16 + m16) * 32 + quad * 8];
#pragma unroll
        for (int i = 0; i < 4; ++i)
#pragma unroll
            for (int j = 0; j < 4; ++j)
                acc[i][j] = __builtin_amdgcn_mfma_f32_16x16x32_bf16(
                    af[i], bfv[j], acc[i][j], 0, 0, 0);
        __syncthreads();
    }

    // C/D layout (m89-verified): col(n)=lane&15, row(m)=(lane>>4)*4+reg
    if (STORE == 0) {
        u16* C = (u16*)Cout + (size_t)bz * sC;
#pragma unroll
        for (int i = 0; i < 4; ++i) {
            int m = m0 + wm + i * 16 + quad * 4;
#pragma unroll
            for (int j = 0; j < 4; ++j) {
                int n = n0 + wn + j * 16 + m16;
                float bn_ = (bias_mode == 1) ? bias[n] : 0.f;
#pragma unroll
                for (int r = 0; r < 4; ++r) {
                    float v = acc[i][j][r] +
                              ((bias_mode == 2) ? bias[m + r] : bn_);
                    C[(size_t)(m + r) * ldC + n] = f2bf(v);
                }
            }
        }
    } else {
        float* C = (float*)Cout + (size_t)bz * sC;
#pragma unroll
        for (int i = 0; i < 4; ++i) {
            int m = m0 + wm + i * 16 + quad * 4;
#pragma unroll
            for (int j = 0; j < 4; ++j) {
                int n = n0 + wn + j * 16 + m16;
                float bn_ = (bias_mode == 1) ? bias[n] : 0.f;
#pragma unroll
                for (int r = 0; r < 4; ++r) {
                    float v = acc[i][j][r] +
                              ((bias_mode == 2) ? bias[m + r] : bn_);
                    C[(size_t)(m + r) * ldC + n] = v;
                }
            }
        }
    }
}

// ---------------------------------------------------------------------------
// In-place row softmax on bf16 S (rows of 2304). 192 threads, 12 elems each.
// ---------------------------------------------------------------------------
__global__ __launch_bounds__(192)
void softmax_rows(u16* __restrict__ S) {
    const int b = blockIdx.x & 7;
    const int q = blockIdx.x >> 3;
    u16* row = S + ((size_t)b * HWc + q) * (size_t)HWc;
    const int tid = threadIdx.x;

    float v[12];
#pragma unroll
    for (int c = 0; c < 3; ++c) {
        uint2 raw = *(const uint2*)&row[(c * 192 + tid) * 4];
        v[c * 4 + 0] = bf2f((u16)(raw.x & 0xffff));
        v[c * 4 + 1] = bf2f((u16)(raw.x >> 16));
        v[c * 4 + 2] = bf2f((u16)(raw.y & 0xffff));
        v[c * 4 + 3] = bf2f((u16)(raw.y >> 16));
    }
    float m = v[0];
#pragma unroll
    for (int i = 1; i < 12; ++i) m = fmaxf(m, v[i]);
#pragma unroll
    for (int off = 32; off; off >>= 1) m = fmaxf(m, __shfl_down(m, off, 64));
    __shared__ float redm[3], reds[3];
    if ((tid & 63) == 0) redm[tid >> 6] = m;
    __syncthreads();
    m = fmaxf(fmaxf(redm[0], redm[1]), redm[2]);

    float s = 0.f;
#pragma unroll
    for (int i = 0; i < 12; ++i) { v[i] = __expf(v[i] - m); s += v[i]; }
#pragma unroll
    for (int off = 32; off; off >>= 1) s += __shfl_down(s, off, 64);
    if ((tid & 63) == 0) reds[tid >> 6] = s;
    __syncthreads();
    const float rinv = 1.0f / (reds[0] + reds[1] + reds[2]);

#pragma unroll
    for (int c = 0; c < 3; ++c) {
        uint2 o;
        o.x = (uint32_t)f2bf(v[c * 4 + 0] * rinv) |
              ((uint32_t)f2bf(v[c * 4 + 1] * rinv) << 16);
        o.y = (uint32_t)f2bf(v[c * 4 + 2] * rinv) |
              ((uint32_t)f2bf(v[c * 4 + 3] * rinv) << 16);
        *(uint2*)&row[(c * 192 + tid) * 4] = o;
    }
}

// ---------------------------------------------------------------------------
// BN stats: one block per channel o. stats[o]=mean, stats[C+o]=rstd
// ---------------------------------------------------------------------------
__global__ __launch_bounds__(256)
void bn_stats(const float* __restrict__ wy, float* __restrict__ stats) {
    const int o = blockIdx.x;
    const int tid = threadIdx.x;
    float s0 = 0.f, s1 = 0.f;
    for (int b = 0; b < Bn; ++b) {
        const float* r = wy + (size_t)b * Cc * HWc + (size_t)o * HWc;
        for (int p = tid; p < HWc; p += 256) {
            float v = r[p];
            s0 += v;
            s1 = fmaf(v, v, s1);
        }
    }
#pragma unroll
    for (int off = 32; off; off >>= 1) {
        s0 += __shfl_down(s0, off, 64);
        s1 += __shfl_down(s1, off, 64);
    }
    __shared__ float r0[4], r1[4];
    if ((tid & 63) == 0) { r0[tid >> 6] = s0; r1[tid >> 6] = s1; }
    __syncthreads();
    if (tid == 0) {
        float sum = r0[0] + r0[1] + r0[2] + r0[3];
        float sq  = r1[0] + r1[1] + r1[2] + r1[3];
        const float N = (float)(Bn * HWc);
        float mean = sum / N;
        float var  = sq / N - mean * mean;
        stats[o]      = mean;
        stats[Cc + o] = rsqrtf(var + BN_EPS);
    }
}

__global__ __launch_bounds__(256)
void bn_apply(const float* __restrict__ wy, const float* __restrict__ x,
              const float* __restrict__ stats, const float* __restrict__ gamma,
              const float* __restrict__ beta, float* __restrict__ out) {
    const size_t i4 = (size_t)blockIdx.x * 256 + threadIdx.x;
    const size_t base = i4 * 4;
    const int o = (int)((base / HWc) % Cc);
    const float mean = stats[o];
    const float rstd = stats[Cc + o];
    const float ga = gamma[o];
    const float be = beta[o];
    const float4 w4 = ((const float4*)wy)[i4];
    const float4 x4 = ((const float4*)x)[i4];
    float4 r;
    r.x = (w4.x - mean) * rstd * ga + be + x4.x;
    r.y = (w4.y - mean) * rstd * ga + be + x4.y;
    r.z = (w4.z - mean) * rstd * ga + be + x4.z;
    r.w = (w4.w - mean) * rstd * ga + be + x4.w;
    ((float4*)out)[i4] = r;
}

// ---------------------------------------------------------------------------
extern "C" void kernel_launch(void* const* d_in, const int* in_sizes, int n_in,
                              void* d_out, int out_size, void* d_ws, size_t ws_size,
                              hipStream_t stream) {
    const float* x     = (const float*)d_in[0];
    const float* g_w   = (const float*)d_in[1];
    const float* g_b   = (const float*)d_in[2];
    const float* th_w  = (const float*)d_in[3];
    const float* th_b  = (const float*)d_in[4];
    const float* ph_w  = (const float*)d_in[5];
    const float* ph_b  = (const float*)d_in[6];
    const float* w_w   = (const float*)d_in[7];
    const float* w_b   = (const float*)d_in[8];
    const float* gamma = (const float*)d_in[9];
    const float* beta  = (const float*)d_in[10];

    // Workspace aliasing (total 113,246,208 B + stats, within known-good bound):
    //  [0        , 9.44M )  tht bf16 (HW,IC)   -> later y bf16 (HW,IC)
    //  [9.44M    , 18.87M)  pht bf16 (HW,IC)
    //  [18.87M   , 28.31M)  g   bf16 (IC,HW)
    //  [28.31M   , 113.25M) S   bf16 (HW,HW); before S-gemm this region hosts
    //        xt bf16 (B,HW,C) at +0 (18.87M) and wbf1 (th/ph/g weights) at +18.87M;
    //        after PV it hosts wy fp32 (37.75M) at +0, wbf2 at +37.75M, stats after.
    char* base = (char*)d_ws;
    const size_t SZT = (size_t)Bn * HWc * ICc * 2;       // 9,437,184
    u16* tht = (u16*)base;
    u16* pht = (u16*)(base + SZT);
    u16* g   = (u16*)(base + 2 * SZT);
    char* Sreg = base + 3 * SZT;                          // 28,311,552
    u16* S    = (u16*)Sreg;                               // 84,934,656 B
    u16* xt   = (u16*)Sreg;                               // 18,874,368 B (pre-S)
    u16* wbf1 = (u16*)(Sreg + (size_t)Bn * HWc * Cc * 2); // 786,432 B (pre-S)
    u16* y    = (u16*)base;                               // over tht (post-S-gemm... post-PV inputs ok: PV reads S,g)
    float* wy = (float*)Sreg;                             // 37,748,736 B (post-PV)
    u16* wbf2 = (u16*)(Sreg + (size_t)Bn * Cc * HWc * 4); // 262,144 B (post-PV)
    float* stats = (float*)(Sreg + (size_t)Bn * Cc * HWc * 4 + 262144);

    dim3 blk(256);

    // weights -> bf16: wbf1 = [th | ph | g]
    cast3_weights<<<dim3(384), blk, 0, stream>>>(th_w, ph_w, g_w, wbf1);
    // x -> xt (B,HW,C) bf16
    transpose_cast_x<<<dim3(HWc / 32, Cc / 32, Bn), blk, 0, stream>>>(x, xt);

    const u16* thwb = wbf1;
    const u16* phwb = wbf1 + 131072;
    const u16* gwb  = wbf1 + 262144;

    // tht[q][ic] = sum_c xt[q][c] * th_w[ic][c] + th_b[ic]   (M=2304,N=256,K=512)
    mfma_gemm<0><<<dim3(2, 18, Bn), blk, 0, stream>>>(
        xt, thwb, tht, th_b, 1, Cc, Cc, Cc, ICc,
        (size_t)HWc * Cc, 0, (size_t)HWc * ICc);
    mfma_gemm<0><<<dim3(2, 18, Bn), blk, 0, stream>>>(
        xt, phwb, pht, ph_b, 1, Cc, Cc, Cc, ICc,
        (size_t)HWc * Cc, 0, (size_t)HWc * ICc);
    // g[ic][p] = sum_c g_w[ic][c] * xt[p][c] + g_b[ic]       (M=256,N=2304,K=512)
    mfma_gemm<0><<<dim3(18, 2, Bn), blk, 0, stream>>>(
        gwb, xt, g, g_b, 2, Cc, Cc, Cc, HWc,
        0, (size_t)HWc * Cc, (size_t)ICc * HWc);

    // S = tht . pht^T   (M=N=2304, K=256)
    mfma_gemm<0><<<dim3(18, 18, Bn), blk, 0, stream>>>(
        tht, pht, S, nullptr, 0, ICc, ICc, ICc, HWc,
        (size_t)HWc * ICc, (size_t)HWc * ICc, (size_t)HWc * HWc);

    // softmax rows, in place
    softmax_rows<<<dim3(Bn * HWc), dim3(192), 0, stream>>>(S);

    // y[q][ic] = sum_k P[q][k] g[ic][k]   (M=2304, N=256, K=2304), bf16 out
    mfma_gemm<0><<<dim3(2, 18, Bn), blk, 0, stream>>>(
        S, g, y, nullptr, 0, HWc, HWc, HWc, ICc,
        (size_t)HWc * HWc, (size_t)ICc * HWc, (size_t)HWc * ICc);

    // w_w -> bf16 (into dead S region, after PV)
    cast1_weight<<<dim3(128), blk, 0, stream>>>(w_w, wbf2);

    // wy[o][p] = sum_ic w_w[o][ic] * y[p][ic] + w_b[o]  (M=512,N=2304,K=256), fp32
    mfma_gemm<1><<<dim3(18, 4, Bn), blk, 0, stream>>>(
        wbf2, y, wy, w_b, 2, ICc, ICc, ICc, HWc,
        0, (size_t)HWc * ICc, (size_t)Cc * HWc);

    // BatchNorm (training stats) + affine + residual
    bn_stats<<<dim3(Cc), blk, 0, stream>>>(wy, stats);
    bn_apply<<<dim3((Bn * Cc * HWc) / 4 / 256), blk, 0, stream>>>(
        wy, x, stats, gamma, beta, (float*)d_out);
}

// Round 4
// 341.054 us; speedup vs baseline: 9.4604x; 1.1044x over previous
//
#include <hip/hip_runtime.h>
#include <hip/hip_bf16.h>
#include <stdint.h>

// Problem constants (fixed by setup_inputs)
constexpr int Bn  = 8;
constexpr int Cc  = 512;
constexpr int ICc = 256;
constexpr int HWc = 48 * 48;           // 2304
constexpr float BN_EPS = 1e-5f;

typedef unsigned short u16;
typedef __attribute__((ext_vector_type(8))) short short8;   // 8 bf16 (4 VGPRs)
typedef __attribute__((ext_vector_type(4))) float f32x4;    // MFMA C/D frag

__device__ __forceinline__ u16 f2bf(float f) {
    uint32_t u = __builtin_bit_cast(uint32_t, f);
    u += 0x7fffu + ((u >> 16) & 1u);     // RNE
    return (u16)(u >> 16);
}
__device__ __forceinline__ float bf2f(u16 h) {
    uint32_t u = ((uint32_t)h) << 16;
    return __builtin_bit_cast(float, u);
}
// async global->LDS, 16B per lane; lds dst is wave-uniform base (HW adds lane*16)
__device__ __forceinline__ void load_lds16(const void* g, void* l) {
    __builtin_amdgcn_global_load_lds(
        (const __attribute__((address_space(1))) void*)(uintptr_t)g,
        (__attribute__((address_space(3))) void*)(uintptr_t)l, 16, 0, 0);
}

// ---------------------------------------------------------------------------
// Front cast: thph_w bf16 (rows 0..255=th_w, 256..511=ph_w), g_w bf16,
// bias_thph fp32 [th_b | ph_b].
// ---------------------------------------------------------------------------
__global__ __launch_bounds__(256)
void cast_front(const float* __restrict__ th_w, const float* __restrict__ ph_w,
                const float* __restrict__ g_w, const float* __restrict__ th_b,
                const float* __restrict__ ph_b, u16* __restrict__ wcat,
                float* __restrict__ bias_thph) {
    int idx = blockIdx.x * 256 + threadIdx.x;
    if (idx < 98304) {                           // ushort4 casts
        const float4* src;
        if (idx < 32768)       src = (const float4*)th_w + idx;
        else if (idx < 65536)  src = (const float4*)ph_w + (idx - 32768);
        else                   src = (const float4*)g_w  + (idx - 65536);
        float4 v = *src;
        ushort4 o;
        o.x = f2bf(v.x); o.y = f2bf(v.y); o.z = f2bf(v.z); o.w = f2bf(v.w);
        ((ushort4*)wcat)[idx] = o;
    } else if (idx < 98816) {                    // 512 bias floats
        int i = idx - 98304;
        bias_thph[i] = (i < 256) ? th_b[i] : ph_b[i - 256];
    }
}

__global__ __launch_bounds__(256)
void cast_w(const float* __restrict__ a, u16* __restrict__ out) {
    int idx = blockIdx.x * 256 + threadIdx.x;    // 0..32767
    float4 v = ((const float4*)a)[idx];
    ushort4 o;
    o.x = f2bf(v.x); o.y = f2bf(v.y); o.z = f2bf(v.z); o.w = f2bf(v.w);
    ((ushort4*)out)[idx] = o;
}

// ---------------------------------------------------------------------------
// x (B,C,HW) fp32 -> xt (B,HW,C) bf16, 64c x 32p LDS-tiled, ushort2 stores
// ---------------------------------------------------------------------------
__global__ __launch_bounds__(256)
void transpose_cast_x(const float* __restrict__ x, u16* __restrict__ xt) {
    __shared__ float t[64][33];
    const int b = blockIdx.z;
    const int p0 = blockIdx.x * 32;     // HW dir
    const int c0 = blockIdx.y * 64;     // C dir
    const int tx = threadIdx.x & 31, ty = threadIdx.x >> 5;   // ty 0..7
    const float* xb = x + (size_t)b * Cc * HWc;
#pragma unroll
    for (int r = 0; r < 8; ++r)
        t[r * 8 + ty][tx] = xb[(size_t)(c0 + r * 8 + ty) * HWc + p0 + tx];
    __syncthreads();
    u16* xtb = xt + (size_t)b * HWc * Cc;
    const int cc = (threadIdx.x & 31) * 2, pp = threadIdx.x >> 5;
#pragma unroll
    for (int r = 0; r < 4; ++r) {
        int p = r * 8 + pp;
        ushort2 v;
        v.x = f2bf(t[cc][p]);
        v.y = f2bf(t[cc + 1][p]);
        *(ushort2*)&xtb[(size_t)(p0 + p) * Cc + c0 + cc] = v;
    }
}

// ---------------------------------------------------------------------------
// bf16 MFMA GEMM: C[m][n] = sum_k A[m][k] * B[n][k] (+ bias)
//   A: (M,K) bf16, B: (N,K) bf16, both K-contiguous.
//   TM=128: 128x128 tile, wave layout 2x2 (64x64 each).
//   TM=64 :  64x128 tile, wave layout 2x2 (32x64 each) -> 2x blocks for
//            occupancy-starved shapes (PV gemm: 288 -> 576 blocks).
// STORE==0: bf16 C; STORE==1: fp32 C. STATS: fused per-channel(m) sum/sumsq
// via 16-lane shuffle reduce + atomicAdd (BatchNorm over n and batch).
// bias_mode: 0 none, 1 per-n, 2 per-m.
// ---------------------------------------------------------------------------
template <int TM, int STORE, bool STATS>
__global__ __launch_bounds__(256, 2)
void mfma_gemm(const u16* __restrict__ A, const u16* __restrict__ B,
               void* __restrict__ Cout, const float* __restrict__ bias,
               int bias_mode, int K, int ldA, int ldB, int ldC,
               size_t sA, size_t sB, size_t sC,
               float* __restrict__ s0g, float* __restrict__ s1g) {
    constexpr int MI = TM / 32;                  // 4 (TM=128) or 2 (TM=64)
    __shared__ __align__(16) u16 As[TM * 32];
    __shared__ __align__(16) u16 Bs[128 * 32];
    const int bz = blockIdx.z;
    const int m0 = blockIdx.y * TM, n0 = blockIdx.x * 128;
    const u16* Ab = A + (size_t)bz * sA + (size_t)m0 * ldA;
    const u16* Bb = B + (size_t)bz * sB + (size_t)n0 * ldB;
    const int tid = threadIdx.x, lane = tid & 63, w = tid >> 6;
    const int wm = (w & 1) * (TM / 2);
    const int wn = (w >> 1) * 64;
    const int quad = lane >> 4, m16 = lane & 15;

    f32x4 acc[MI][4];
#pragma unroll
    for (int i = 0; i < MI; ++i)
#pragma unroll
        for (int j = 0; j < 4; ++j) acc[i][j] = (f32x4){0.f, 0.f, 0.f, 0.f};

    // staging: linear slot L -> row = L>>2, k-chunk = (L&3)*8
    const int L0 = 2 * w * 64 + lane, L1 = L0 + 64;
    const int br0 = L0 >> 2, bc0 = (L0 & 3) * 8;
    const int br1 = L1 >> 2, bc1 = (L1 & 3) * 8;
    const int ar0 = (TM == 128) ? br0 : (tid >> 2);
    const int ac0 = (TM == 128) ? bc0 : (tid & 3) * 8;

    for (int k0 = 0; k0 < K; k0 += 32) {
        if (TM == 128) {
            load_lds16(Ab + (size_t)ar0 * ldA + k0 + ac0, &As[2 * w * 512]);
            load_lds16(Ab + (size_t)br1 * ldA + k0 + bc1, &As[(2 * w + 1) * 512]);
        } else {
            load_lds16(Ab + (size_t)ar0 * ldA + k0 + ac0, &As[w * 512]);
        }
        load_lds16(Bb + (size_t)br0 * ldB + k0 + bc0, &Bs[2 * w * 512]);
        load_lds16(Bb + (size_t)br1 * ldB + k0 + bc1, &Bs[(2 * w + 1) * 512]);
        __syncthreads();

        short8 af[MI], bfv[4];
#pragma unroll
        for (int i = 0; i < MI; ++i)
            af[i] = *(const short8*)&As[(wm + i * 16 + m16) * 32 + quad * 8];
#pragma unroll
        for (int j = 0; j < 4; ++j)
            bfv[j] = *(const short8*)&Bs[(wn + j * 16 + m16) * 32 + quad * 8];
#pragma unroll
        for (int i = 0; i < MI; ++i)
#pragma unroll
            for (int j = 0; j < 4; ++j)
                acc[i][j] = __builtin_amdgcn_mfma_f32_16x16x32_bf16(
                    af[i], bfv[j], acc[i][j], 0, 0, 0);
        __syncthreads();
    }

    // bias into acc (C/D layout m89: col n = lane&15, row m = quad*4 + reg)
    if (bias_mode) {
#pragma unroll
        for (int i = 0; i < MI; ++i)
#pragma unroll
            for (int j = 0; j < 4; ++j)
#pragma unroll
                for (int r = 0; r < 4; ++r)
                    acc[i][j][r] += (bias_mode == 2)
                        ? bias[m0 + wm + i * 16 + quad * 4 + r]
                        : bias[n0 + wn + j * 16 + m16];
    }

    if (STORE == 0) {
        u16* C = (u16*)Cout + (size_t)bz * sC;
#pragma unroll
        for (int i = 0; i < MI; ++i) {
            int m = m0 + wm + i * 16 + quad * 4;
#pragma unroll
            for (int j = 0; j < 4; ++j) {
                int n = n0 + wn + j * 16 + m16;
#pragma unroll
                for (int r = 0; r < 4; ++r)
                    C[(size_t)(m + r) * ldC + n] = f2bf(acc[i][j][r]);
            }
        }
    } else {
        float* C = (float*)Cout + (size_t)bz * sC;
#pragma unroll
        for (int i = 0; i < MI; ++i) {
            int m = m0 + wm + i * 16 + quad * 4;
#pragma unroll
            for (int j = 0; j < 4; ++j) {
                int n = n0 + wn + j * 16 + m16;
#pragma unroll
                for (int r = 0; r < 4; ++r)
                    C[(size_t)(m + r) * ldC + n] = acc[i][j][r];
            }
        }
    }

    if (STATS) {
        // per-row partial sums over this wave's 64 n-cols, then atomic
#pragma unroll
        for (int i = 0; i < MI; ++i) {
#pragma unroll
            for (int r = 0; r < 4; ++r) {
                float v0 = 0.f, v1 = 0.f;
#pragma unroll
                for (int j = 0; j < 4; ++j) {
                    float v = acc[i][j][r];
                    v0 += v;
                    v1 = fmaf(v, v, v1);
                }
#pragma unroll
                for (int off = 8; off; off >>= 1) {
                    v0 += __shfl_down(v0, off, 16);
                    v1 += __shfl_down(v1, off, 16);
                }
                if (m16 == 0) {
                    int m = m0 + wm + i * 16 + quad * 4 + r;
                    atomicAdd(&s0g[m], v0);
                    atomicAdd(&s1g[m], v1);
                }
            }
        }
    }
}

// ---------------------------------------------------------------------------
// In-place row softmax on bf16 S (rows of 2304). 192 threads, 12 elems each.
// ---------------------------------------------------------------------------
__global__ __launch_bounds__(192)
void softmax_rows(u16* __restrict__ S) {
    const int b = blockIdx.x & 7;
    const int q = blockIdx.x >> 3;
    u16* row = S + ((size_t)b * HWc + q) * (size_t)HWc;
    const int tid = threadIdx.x;

    float v[12];
#pragma unroll
    for (int c = 0; c < 3; ++c) {
        uint2 raw = *(const uint2*)&row[(c * 192 + tid) * 4];
        v[c * 4 + 0] = bf2f((u16)(raw.x & 0xffff));
        v[c * 4 + 1] = bf2f((u16)(raw.x >> 16));
        v[c * 4 + 2] = bf2f((u16)(raw.y & 0xffff));
        v[c * 4 + 3] = bf2f((u16)(raw.y >> 16));
    }
    float m = v[0];
#pragma unroll
    for (int i = 1; i < 12; ++i) m = fmaxf(m, v[i]);
#pragma unroll
    for (int off = 32; off; off >>= 1) m = fmaxf(m, __shfl_down(m, off, 64));
    __shared__ float redm[3], reds[3];
    if ((tid & 63) == 0) redm[tid >> 6] = m;
    __syncthreads();
    m = fmaxf(fmaxf(redm[0], redm[1]), redm[2]);

    float s = 0.f;
#pragma unroll
    for (int i = 0; i < 12; ++i) { v[i] = __expf(v[i] - m); s += v[i]; }
#pragma unroll
    for (int off = 32; off; off >>= 1) s += __shfl_down(s, off, 64);
    if ((tid & 63) == 0) reds[tid >> 6] = s;
    __syncthreads();
    const float rinv = 1.0f / (reds[0] + reds[1] + reds[2]);

#pragma unroll
    for (int c = 0; c < 3; ++c) {
        uint2 o;
        o.x = (uint32_t)f2bf(v[c * 4 + 0] * rinv) |
              ((uint32_t)f2bf(v[c * 4 + 1] * rinv) << 16);
        o.y = (uint32_t)f2bf(v[c * 4 + 2] * rinv) |
              ((uint32_t)f2bf(v[c * 4 + 3] * rinv) << 16);
        *(uint2*)&row[(c * 192 + tid) * 4] = o;
    }
}

// ---------------------------------------------------------------------------
// Normalize (from raw sums) + affine + residual, float4 vectorized
// ---------------------------------------------------------------------------
__global__ __launch_bounds__(256)
void bn_apply(const float* __restrict__ wy, const float* __restrict__ x,
              const float* __restrict__ s0, const float* __restrict__ s1,
              const float* __restrict__ gamma, const float* __restrict__ beta,
              float* __restrict__ out) {
    const size_t i4 = (size_t)blockIdx.x * 256 + threadIdx.x;
    const size_t base = i4 * 4;
    const int o = (int)((base / HWc) % Cc);
    const float N = (float)(Bn * HWc);
    const float mean = s0[o] / N;
    const float var  = s1[o] / N - mean * mean;
    const float rstd = rsqrtf(var + BN_EPS);
    const float ga = gamma[o];
    const float be = beta[o];
    const float4 w4 = ((const float4*)wy)[i4];
    const float4 x4 = ((const float4*)x)[i4];
    float4 r;
    r.x = (w4.x - mean) * rstd * ga + be + x4.x;
    r.y = (w4.y - mean) * rstd * ga + be + x4.y;
    r.z = (w4.z - mean) * rstd * ga + be + x4.z;
    r.w = (w4.w - mean) * rstd * ga + be + x4.w;
    ((float4*)out)[i4] = r;
}

// ---------------------------------------------------------------------------
extern "C" void kernel_launch(void* const* d_in, const int* in_sizes, int n_in,
                              void* d_out, int out_size, void* d_ws, size_t ws_size,
                              hipStream_t stream) {
    const float* x     = (const float*)d_in[0];
    const float* g_w   = (const float*)d_in[1];
    const float* g_b   = (const float*)d_in[2];
    const float* th_w  = (const float*)d_in[3];
    const float* th_b  = (const float*)d_in[4];
    const float* ph_w  = (const float*)d_in[5];
    const float* ph_b  = (const float*)d_in[6];
    const float* w_w   = (const float*)d_in[7];
    const float* w_b   = (const float*)d_in[8];
    const float* gamma = (const float*)d_in[9];
    const float* beta  = (const float*)d_in[10];

    // Workspace aliasing (113.25 MB total, same bound as previous rounds):
    //  [0, 18.87M)      thph bf16 (B,HW,512)  -> later y bf16 (B,HW,IC) at [0,9.44M)
    //                   and post-S: wbf2 + stats at [9.44M, ...)
    //  [18.87M, 28.31M) g bf16 (B,IC,HW)
    //  [28.31M, 113.25M) Sreg: pre-S hosts xt bf16 (B,HW,C) + wcat + bias_thph;
    //                   S bf16 (B,HW,HW); post-PV wy fp32 (B,C,HW)
    char* base = (char*)d_ws;
    const size_t SZT = (size_t)Bn * HWc * ICc * 2;        // 9,437,184
    u16* thph = (u16*)base;                               // 18.87 MB
    u16* g    = (u16*)(base + 2 * SZT);                   // 9.44 MB
    char* Sreg = base + 3 * SZT;
    u16* S    = (u16*)Sreg;                               // 84.93 MB
    u16* xt   = (u16*)Sreg;                               // 18.87 MB (pre-S)
    u16* wcat = (u16*)(Sreg + (size_t)Bn * HWc * Cc * 2); // 786 KB (pre-S)
    float* bias_thph = (float*)(Sreg + (size_t)Bn * HWc * Cc * 2 + 786432);
    u16* y    = (u16*)base;                               // 9.44 MB (post-S)
    u16* wbf2 = (u16*)(base + SZT);                       // 262 KB (post-S)
    float* stats = (float*)(base + SZT + 262144);         // 4 KB (post-S)
    float* wy = (float*)Sreg;                             // 37.75 MB (post-PV)

    dim3 blk(256);
    const u16* thphw = wcat;                   // (512,512)
    const u16* gwb   = wcat + 262144;          // (256,512)

    cast_front<<<dim3(386), blk, 0, stream>>>(th_w, ph_w, g_w, th_b, ph_b,
                                              wcat, bias_thph);
    transpose_cast_x<<<dim3(HWc / 32, Cc / 64, Bn), blk, 0, stream>>>(x, xt);

    // thph[q][o] = sum_c xt[q][c]*thph_w[o][c] + bias  (M=2304,N=512,K=512)
    mfma_gemm<128, 0, false><<<dim3(4, 18, Bn), blk, 0, stream>>>(
        xt, thphw, thph, bias_thph, 1, Cc, Cc, Cc, 512,
        (size_t)HWc * Cc, 0, (size_t)HWc * 512, nullptr, nullptr);

    // g[ic][p] = sum_c g_w[ic][c]*xt[p][c] + g_b[ic]   (M=256,N=2304,K=512)
    mfma_gemm<64, 0, false><<<dim3(18, 4, Bn), blk, 0, stream>>>(
        gwb, xt, g, g_b, 2, Cc, Cc, Cc, HWc,
        0, (size_t)HWc * Cc, (size_t)ICc * HWc, nullptr, nullptr);

    // S = tht . pht^T   (M=N=2304, K=256); tht = thph cols 0..255, pht = +256
    mfma_gemm<128, 0, false><<<dim3(18, 18, Bn), blk, 0, stream>>>(
        thph, thph + 256, S, nullptr, 0, ICc, 512, 512, HWc,
        (size_t)HWc * 512, (size_t)HWc * 512, (size_t)HWc * HWc,
        nullptr, nullptr);

    // w_w -> bf16 and zero stats (into regions dead after S-gemm)
    cast_w<<<dim3(128), blk, 0, stream>>>(w_w, wbf2);
    hipMemsetAsync(stats, 0, 2 * Cc * sizeof(float), stream);

    // softmax rows, in place
    softmax_rows<<<dim3(Bn * HWc), dim3(192), 0, stream>>>(S);

    // y[q][ic] = sum_k P[q][k]*g[ic][k]  (M=2304,N=256,K=2304), TM=64: 576 blk
    mfma_gemm<64, 0, false><<<dim3(2, 36, Bn), blk, 0, stream>>>(
        S, g, y, nullptr, 0, HWc, HWc, HWc, ICc,
        (size_t)HWc * HWc, (size_t)ICc * HWc, (size_t)HWc * ICc,
        nullptr, nullptr);

    // wy[o][p] = sum_ic w_w[o][ic]*y[p][ic] + w_b[o]  (M=512,N=2304,K=256)
    // fp32 out + fused BN sum/sumsq
    mfma_gemm<128, 1, true><<<dim3(18, 4, Bn), blk, 0, stream>>>(
        wbf2, y, wy, w_b, 2, ICc, ICc, ICc, HWc,
        0, (size_t)HWc * ICc, (size_t)Cc * HWc, stats, stats + Cc);

    // BatchNorm apply (stats from raw sums) + affine + residual
    bn_apply<<<dim3((Bn * Cc * HWc) / 4 / 256), blk, 0, stream>>>(
        wy, x, stats, stats + Cc, gamma, beta, (float*)d_out);
}